// Round 6
// baseline (11.757 us; speedup 1.0000x reference)
//
#include <hip/hip_runtime.h>
#include <math.h>

// LIF neuron Euler integration, T = 3.5M steps, scalar input current.
//
// Structural insight (verified R1-R5, absmax = 0): every spike resets v to
// exactly V_RESET = 0.0f == initial state, so the fp32 dynamics are exactly
// periodic: spikes[t] = (t > 0 && t % P == 0), P = fp32 Euler steps from v=0
// to first v_new >= 1.0f (P = 220 for I = 1.5).
//
// R6 change (last real-work levers):
//  1. No barrier, no LDS: EVERY thread computes P redundantly (fp32 HW log2
//     seed + ~20 dependent fp64 HW mults ~= 0.13 us, parallel in all waves).
//     Removes __syncthreads() and the block-wide wait on thread 0's cold
//     scalar load.
//  2. One float4 chunk per thread (3418 blocks x 256): no fill loop, every
//     store issues right after the prologue -- max latency tolerance for a
//     14 MB L2-absorbed fill.
// Margin check unchanged: accept closed-form P only if fp64-exact v(P-1),
// v(P) clear the threshold by > 1e-4 + 4e-7*P (worst-case fp32 drift);
// otherwise bit-exact serial fallback (contract off, reference op order,
// alpha = float(double(1e-4)/double(0.02)) == jnp.float32(DT/TAU)).

__device__ __forceinline__ unsigned lif_period_serial(float I, int n_steps) {
#pragma clang fp contract(off)
    const float alpha = (float)(1e-4 / 0.02);  // == jnp.float32(DT / TAU)
    unsigned P = 0;
    float v = 0.0f;
    for (int t = 1; t < n_steps; ++t) {
        float v_new = v + (I - v) * alpha;     // == v + (-v + I)*alpha in IEEE
        if (v_new >= 1.0f) { P = (unsigned)t; break; }
        if (v_new == v) break;                 // converged below threshold
        v = v_new;
    }
    return P;
}

__device__ __forceinline__ double pow_u(double b, unsigned e) {
    double r = 1.0, p = b;
    while (e) { if (e & 1u) r *= p; p *= p; e >>= 1; }
    return r;
}

__device__ __forceinline__ unsigned lif_period(float I, int n) {
    const float alpha_f = (float)(1e-4 / 0.02);

    if (I < 0.999f) return 0u;        // fixed point v -> I, never crosses

    if (I >= 1.001f) {
        // fp32 HW-transcendental seed (error ~5e-5 steps; need only +-1)
        const float x   = 1.0f - 1.0f / I;
        const float nn  = log2f(x) / log2f(1.0f - alpha_f);
        long m0 = (long)nn - 2;
        if (m0 < 1) m0 = 1;

        // exact margins via fp64 HW mults only (no libm)
        const double beta = 1.0 - (double)alpha_f;
        const double dI   = (double)I;
        double bm    = pow_u(beta, (unsigned)(m0 - 1));
        double vprev = dI * (1.0 - bm);
        for (long m = m0; m <= m0 + 6; ++m) {
            bm *= beta;
            double vm = dI * (1.0 - bm);
            if (vm >= 1.0) {
                const double margin = 1e-4 + 4e-7 * (double)m;
                if ((1.0 - vprev) > margin && (vm - 1.0) > margin)
                    return (unsigned)m;
                break;                // ambiguous -> serial fallback
            }
            vprev = vm;
        }
    }
    return lif_period_serial(I, n);   // bit-exact fallback
}

__global__ void lif_kernel(const float* __restrict__ input_current,
                           float* __restrict__ out, int n) {
    const unsigned i0 = (blockIdx.x * blockDim.x + threadIdx.x) * 4u;
    const unsigned un = (unsigned)n;
    if (i0 >= un) return;

    const unsigned P = lif_period(input_current[0], n);

    float4 vals = make_float4(0.f, 0.f, 0.f, 0.f);
    if (P != 0u) {
        unsigned r = i0 % P;          // one integer division per thread
        vals.x = (r == 0u && i0 != 0u) ? 1.0f : 0.0f;
        r = (r + 1u == P) ? 0u : r + 1u;
        vals.y = (r == 0u) ? 1.0f : 0.0f;
        r = (r + 1u == P) ? 0u : r + 1u;
        vals.z = (r == 0u) ? 1.0f : 0.0f;
        r = (r + 1u == P) ? 0u : r + 1u;
        vals.w = (r == 0u) ? 1.0f : 0.0f;
    }

    if (i0 + 4u <= un) {
        *reinterpret_cast<float4*>(out + i0) = vals;
    } else {
        const float v[4] = {vals.x, vals.y, vals.z, vals.w};
        for (unsigned j = 0; i0 + j < un; ++j) out[i0 + j] = v[j];
    }
}

extern "C" void kernel_launch(void* const* d_in, const int* in_sizes, int n_in,
                              void* d_out, int out_size, void* d_ws, size_t ws_size,
                              hipStream_t stream) {
    const float* d_I = (const float*)d_in[0];   // input_current (scalar)
    float* out = (float*)d_out;                 // T fp32 spikes

    const int nchunks = (out_size + 3) / 4;             // one float4 per thread
    const int nblocks = (nchunks + 255) / 256;
    lif_kernel<<<nblocks, 256, 0, stream>>>(d_I, out, out_size);
}